// Round 9
// baseline (140.416 us; speedup 1.0000x reference)
//
#include <hip/hip_runtime.h>

#define NN 8192
#define DD 128
#define MAXCLS 64   // max members per class; Binom(8192,1/1024) mean 8 -> P(>64) negligible
#define NCHUNK 8    // j-chunks in the GEMM phase
#define NBLK 256    // fused grid: 1 block/CU x 256 CU, co-resident by construction
#define TPB  512    // 8 waves/block
#define LOG2E 1.4426950408889634f
#define E1    2.718281828459045f   // e^margin, margin = 1

typedef __attribute__((ext_vector_type(8))) short bf16x8;
typedef __attribute__((ext_vector_type(4))) float f32x4;

#if __has_builtin(__builtin_amdgcn_exp2f)
#define EXP2F(x) __builtin_amdgcn_exp2f(x)
#else
#define EXP2F(x) exp2f(x)
#endif

// async global->LDS 16B: per-lane global address, LDS dest = wave-uniform base + lane*16
__device__ __forceinline__ void load16_lds(const unsigned short* g, unsigned short* l) {
    __builtin_amdgcn_global_load_lds(
        (const __attribute__((address_space(1))) unsigned int*)g,
        (__attribute__((address_space(3))) unsigned int*)l,
        16, 0, 0);
}

__device__ __forceinline__ unsigned short f2bf(float x) {
    unsigned u = __float_as_uint(x);
    u = (u + 0x7FFFu + ((u >> 16) & 1u)) >> 16;
    return (unsigned short)u;
}

// sc1 write-through stores: relaxed AGENT-scope atomic stores write at the coherent
// point (LLC) and never allocate in L1/L2. ALL cross-phase data uses these ->
// no L2 ever holds a dirty OR stale copy of cross-phase data -> barriers need NO
// cache maintenance at all.
__device__ __forceinline__ void st_agent(float* p, float v) {
    __hip_atomic_store(p, v, __ATOMIC_RELAXED, __HIP_MEMORY_SCOPE_AGENT);
}
__device__ __forceinline__ void st_agent(int* p, int v) {
    __hip_atomic_store(p, v, __ATOMIC_RELAXED, __HIP_MEMORY_SCOPE_AGENT);
}
__device__ __forceinline__ void st_agent(unsigned int* p, unsigned int v) {
    __hip_atomic_store(p, v, __ATOMIC_RELAXED, __HIP_MEMORY_SCOPE_AGENT);
}
__device__ __forceinline__ void st_agent(unsigned long long* p, unsigned long long v) {
    __hip_atomic_store(p, v, __ATOMIC_RELAXED, __HIP_MEMORY_SCOPE_AGENT);
}
__device__ __forceinline__ unsigned int ld_agent(const unsigned int* p) {
    return __hip_atomic_load(p, __ATOMIC_RELAXED, __HIP_MEMORY_SCOPE_AGENT);
}

// HW_REG_XCC_ID (id=20) [measured: learn_hip m09]. Correctness only needs
// per-block consistency (grouping key), not accuracy.
__device__ __forceinline__ int xcd_id() {
    return (int)(__builtin_amdgcn_s_getreg(20 | (0 << 6) | (31 << 11)) & 7u);
}

// ---------------- device-scope grid barrier, zero cache maintenance ----------------
// (R6 structure, absmax-0 verified x3): 128B-separated counters, one relay per XCD
// claimed once, relaxed arrivals, no release/acquire/inv (all cross-phase data sc1 +
// first-touch-after-sync). Spins carry ~7ms timeout escapes: failure => wrong
// answer (absmax flags it), never a hung container.
__device__ __forceinline__ void grid_sync(int* subcnt, int* root, unsigned int* gen,
                                          unsigned int* doneg, int relay, int myxcd,
                                          int sub) {
    __syncthreads();   // every wave drains vmcnt -> all sc1 stores complete at LLC
    if (threadIdx.x == 0) {
        unsigned int g = ld_agent(gen);   // gen can't advance past g before we arrive
        int v = __hip_atomic_fetch_add(&subcnt[sub * 32], 1,
                                       __ATOMIC_RELAXED, __HIP_MEMORY_SCOPE_AGENT);
        if (v == (NBLK / 8) - 1) {           // last arrival on this sub-counter
            __hip_atomic_store(&subcnt[sub * 32], 0, __ATOMIC_RELAXED, __HIP_MEMORY_SCOPE_AGENT);
            int r = __hip_atomic_fetch_add(root, 1, __ATOMIC_RELAXED, __HIP_MEMORY_SCOPE_AGENT);
            if (r == 7) {                    // whole grid arrived
                __hip_atomic_store(root, 0, __ATOMIC_RELAXED, __HIP_MEMORY_SCOPE_AGENT);
                st_agent(gen, g + 1u);
            }
        }
        if (relay) {
            long long t0 = clock64();
            while (ld_agent(gen) == g) {
                __builtin_amdgcn_s_sleep(1);
                if (clock64() - t0 > (1LL << 24)) break;   // ~7ms escape hatch
            }
            st_agent(&doneg[myxcd * 32], g + 1u);          // repost on per-XCD line
        } else {
            long long t1 = clock64();
            while ((int)(ld_agent(&doneg[myxcd * 32]) - (g + 1u)) < 0) {
                __builtin_amdgcn_s_sleep(1);
                if (clock64() - t1 > (1LL << 24)) break;
            }
        }
    }
    __syncthreads();
}

// ---------------- fused kernel: convert+bucket | gemm+vsum | pairs | finalize ----------------
// R9: phase B restructured per the m233/m218 measured pathology (2-phase stage/
// barrier structure = ~70% overhead; fix = interleave load-ISSUE inside the MFMA
// phases, counted waits only): TRI-buffered B tiles (3x32KB). Tile jt reads buf
// (jt+2)%3; staging for jt+2 writes buf (jt+1)%3 (never the buffer being read) ->
// the 4 staging loads issue one-per-ks INSIDE the MFMA loop; ONE barrier per tile
// (was two) preceded by counted vmcnt(4). Prologue: A-lo/A-hi/B0 staged in one
// round (A register-resident thereafter). Phases A/C/finalize byte-identical to R8.
__global__ __launch_bounds__(TPB, 2) void ml_fused_kernel(
    const float* __restrict__ a, const float* __restrict__ b,
    const int* __restrict__ labels,
    unsigned short* __restrict__ abf, unsigned short* __restrict__ bbf,
    int* __restrict__ cnt, int* __restrict__ list,
    float* __restrict__ Vp,
    float* __restrict__ classLoss, int* __restrict__ classCnt,
    float* __restrict__ out,
    int* subcnt, int* root, unsigned int* gen,
    int* claim, unsigned int* doneg)
{
    // LDS: [0,98304) = Bs[3][128*DD] (GEMM tri-buffer) / [0,73728) phase-C quarters
    //      [98304,98816) = red[4][64] (GEMM cross-wave combine)
    __shared__ char SM[98816];
    unsigned short (*Bs)[128 * DD] = (unsigned short (*)[128 * DD])SM;
    float* red = (float*)(SM + 98304);

    const int tid = threadIdx.x;
    const int bid = blockIdx.x;
    const int sub = bid & 7;

    // one-time relay claim (first block per XCD value wins); only thread 0's copy matters
    int relay = 0, myxcd = 0;
    if (tid == 0) {
        myxcd = xcd_id();
        relay = (__hip_atomic_fetch_add(&claim[myxcd * 32], 1,
                                        __ATOMIC_RELAXED, __HIP_MEMORY_SCOPE_AGENT) == 0);
    }

    // ================= phase A: fp32->bf16 convert + class bucketing =================
#pragma unroll
    for (int it = 0; it < 4; it++) {
        int t = it * (NBLK * TPB) + bid * TPB + tid;   // 0 .. 524287
        const float* src = a;
        unsigned short* dst = abf;
        int idx = t;
        float scale = LOG2E;                           // A rows carry the log2e factor
        if (t >= 262144) { src = b; dst = bbf; idx = t - 262144; scale = 1.0f; }
        float4 v = ((const float4*)src)[idx];
        ushort4 o;
        o.x = f2bf(v.x * scale); o.y = f2bf(v.y * scale);
        o.z = f2bf(v.z * scale); o.w = f2bf(v.w * scale);
        union { ushort4 v4; unsigned long long u; } cvt;
        cvt.v4 = o;
        st_agent(((unsigned long long*)dst) + idx, cvt.u);   // sc1: straight to LLC
        if (t < NN) {
            int c = labels[t];
            int p = atomicAdd(&cnt[c], 1);               // device-scope RMW at LLC
            if (p < MAXCLS) st_agent(&list[c * MAXCLS + p], t);
        }
    }

    grid_sync(subcnt, root, gen, doneg, relay, myxcd, sub);

    // ================= phase B: tri-buffered interleaved GEMM + exp2 row-sum =================
    {
        const int lane = tid & 63;
        const int wv   = tid >> 6;            // 0..7
        const int row0 = (bid >> 3) * 256;    // 32 row-blocks of 256 rows
        const int j0   = (bid & 7) * 1024;    // 8 j-chunks

        const int lr = lane >> 4;      // staging: row-within-4
        const int sp = lane & 15;      // staging: slot
        const int m  = lane & 15;      // mfma row/col lane
        const int q  = lane >> 4;
        const int xr = m & 7;          // read-side swizzle key

        // one staging unit: load I (of 4) of a 128-row tile; wave wv covers rows wv*16+I*4..+3
#define STAGE1(SRCBASE, BUF, I)                                                        \
        {                                                                              \
            int rb = wv * 16 + (I) * 4;                                                \
            int r  = rb + lr;                                                          \
            int cc = sp ^ (r & 7);                                                     \
            load16_lds(&(SRCBASE)[(size_t)r * DD + cc * 8], &Bs[BUF][rb * DD]);        \
        }
#define STAGE128(SRCBASE, BUF)                                                         \
        STAGE1(SRCBASE, BUF, 0) STAGE1(SRCBASE, BUF, 1)                                \
        STAGE1(SRCBASE, BUF, 2) STAGE1(SRCBASE, BUF, 3)

        // ---- prologue: A-lo -> buf0, A-hi -> buf1, B tile0 -> buf2 (12 loads/wave) ----
        STAGE128(&abf[(size_t)row0 * DD], 0)
        STAGE128(&abf[(size_t)(row0 + 128) * DD], 1)
        STAGE128(&bbf[(size_t)j0 * DD], 2)
        asm volatile("s_waitcnt vmcnt(0)" ::: "memory");
        __builtin_amdgcn_s_barrier();          // A + tile0 resident

        const int wi = (wv >> 1) * 64;   // row-quarter of the 256-row block
        const int wj = (wv & 1) * 64;    // col-half of the 128-col tile

        // ---- A fragments -> registers (waves 0-3 from buf0, 4-7 from buf1) ----
        bf16x8 afr[4][4];
        {
            const int abuf  = wv >> 2;
            const int abase = wi - (abuf ? 128 : 0);
#pragma unroll
            for (int ti = 0; ti < 4; ti++)
#pragma unroll
                for (int ks = 0; ks < 4; ks++) {
                    int r   = abase + ti * 16 + m;
                    int pos = (ks * 4 + q) ^ xr;
                    afr[ti][ks] = *(const bf16x8*)(&Bs[abuf][r * DD + pos * 8]);
                }
        }
        asm volatile("s_waitcnt lgkmcnt(0)" ::: "memory");  // afr reads done before reuse
        __builtin_amdgcn_s_barrier();                       // all waves done with buf0/1

        STAGE128(&bbf[(size_t)(j0 + 128) * DD], 0)          // B tile1 -> buf0

        float rs[4][4];
#pragma unroll
        for (int ti = 0; ti < 4; ti++)
#pragma unroll
            for (int rg = 0; rg < 4; rg++) rs[ti][rg] = 0.f;

        const f32x4 zero = {0.f, 0.f, 0.f, 0.f};
        f32x4 acc[4][4];

#define EPILOGUE()                                                                     \
        _Pragma("unroll")                                                              \
        for (int ti = 0; ti < 4; ti++)                                                 \
            _Pragma("unroll")                                                          \
            for (int tj = 0; tj < 4; tj++) {                                           \
                f32x4 c = acc[ti][tj];                                                 \
                rs[ti][0] += EXP2F(c[0]);                                              \
                rs[ti][1] += EXP2F(c[1]);                                              \
                rs[ti][2] += EXP2F(c[2]);                                              \
                rs[ti][3] += EXP2F(c[3]);                                              \
            }

        // one tile: read buf (JT+2)%3; optionally stage tile JT+2 into buf (JT+1)%3,
        // one staging load per ks-phase, issued between the ds_reads and the MFMAs
        // (compiler inserts the fine-grained lgkmcnt for bfr->MFMA itself).
#define TILE(JT, DOSTAGE)                                                              \
        {                                                                              \
            _Pragma("unroll")                                                          \
            for (int ks = 0; ks < 4; ks++) {                                           \
                bf16x8 bfr[4];                                                         \
                _Pragma("unroll")                                                      \
                for (int tj = 0; tj < 4; tj++) {                                       \
                    int r   = wj + tj * 16 + m;                                        \
                    int pos = (ks * 4 + q) ^ xr;                                       \
                    bfr[tj] = *(const bf16x8*)(&Bs[((JT) + 2) % 3][r * DD + pos * 8]); \
                }                                                                      \
                if (DOSTAGE)                                                           \
                    STAGE1(&bbf[(size_t)(j0 + ((JT) + 2) * 128) * DD],                 \
                           ((JT) + 1) % 3, ks)                                         \
                __builtin_amdgcn_s_setprio(1);                                         \
                _Pragma("unroll")                                                      \
                for (int ti = 0; ti < 4; ti++)                                         \
                    _Pragma("unroll")                                                  \
                    for (int tj = 0; tj < 4; tj++)                                     \
                        acc[ti][tj] = __builtin_amdgcn_mfma_f32_16x16x32_bf16(         \
                            afr[ti][ks], bfr[tj], (ks == 0) ? zero : acc[ti][tj],      \
                            0, 0, 0);                                                  \
                __builtin_amdgcn_s_setprio(0);                                         \
            }                                                                          \
            EPILOGUE()                                                                 \
        }

        // steady state: one counted-vmcnt + ONE barrier per tile.
        // outstanding at each wait: 4 old (tile jt+1, must land) + 4 new (jt+2) -> vmcnt(4).
        TILE(0, 1)
        asm volatile("s_waitcnt vmcnt(4)" ::: "memory"); __builtin_amdgcn_s_barrier();
        TILE(1, 1)
        asm volatile("s_waitcnt vmcnt(4)" ::: "memory"); __builtin_amdgcn_s_barrier();
        TILE(2, 1)
        asm volatile("s_waitcnt vmcnt(4)" ::: "memory"); __builtin_amdgcn_s_barrier();
        TILE(3, 1)
        asm volatile("s_waitcnt vmcnt(4)" ::: "memory"); __builtin_amdgcn_s_barrier();
        TILE(4, 1)
        asm volatile("s_waitcnt vmcnt(4)" ::: "memory"); __builtin_amdgcn_s_barrier();
        TILE(5, 1)
        asm volatile("s_waitcnt vmcnt(4)" ::: "memory"); __builtin_amdgcn_s_barrier();
        TILE(6, 0)
        asm volatile("s_waitcnt vmcnt(0)" ::: "memory"); __builtin_amdgcn_s_barrier();
        TILE(7, 0)

#undef TILE
#undef EPILOGUE
#undef STAGE128
#undef STAGE1

        // ---- reduce over the 16 col-lanes ----
#pragma unroll
        for (int ti = 0; ti < 4; ti++)
#pragma unroll
            for (int rg = 0; rg < 4; rg++) {
                float v = rs[ti][rg];
                v += __shfl_xor(v, 1);
                v += __shfl_xor(v, 2);
                v += __shfl_xor(v, 4);
                v += __shfl_xor(v, 8);
                rs[ti][rg] = v;
            }

        // ---- cross-wave combine (odd waves deposit; even waves add + store) ----
        if ((wv & 1) == 1 && m == 0) {
#pragma unroll
            for (int ti = 0; ti < 4; ti++)
#pragma unroll
                for (int rg = 0; rg < 4; rg++)
                    red[(wv >> 1) * 64 + ti * 16 + q * 4 + rg] = rs[ti][rg];
        }
        __syncthreads();
        if ((wv & 1) == 0 && m == 0) {
#pragma unroll
            for (int ti = 0; ti < 4; ti++)
#pragma unroll
                for (int rg = 0; rg < 4; rg++) {
                    int rloc = ti * 16 + q * 4 + rg;
                    st_agent(&Vp[(size_t)(bid & 7) * NN + row0 + wi + rloc],
                             rs[ti][rg] + red[(wv >> 1) * 64 + rloc]);
                }
        }
    }

    grid_sync(subcnt, root, gen, doneg, relay, myxcd, sub);

    // ================= phase C: per-class pairs — BLOCK-COOPERATIVE phase 1 =================
    {
        char* sm = (char*)SM;
        const int h  = tid >> 7;          // quarter 0..3 (owns class c = bid*4+h)
        const int ht = tid & 127;         // tid within quarter
        int*   memH    = (int*)  (sm + h * 18432);           // 256 B
        float* VadjH   = (float*)(sm + h * 18432 + 512);     // 256 B
        float* ScH     = (float*)(sm + h * 18432 + 1024);    // 16 KB
        float* psH     = (float*)(sm + h * 18432 + 17408);   // 8 B (2 waves/quarter)
        int*   csH     = (int*)  (sm + h * 18432 + 17424);   // 8 B
        int*   mcs     = (int*)(sm + 73728);                 // [4]
        int*   cum     = (int*)(sm + 73744);                 // [5]

        const int c = bid * 4 + h;        // classes 0..1023
        int mc = cnt[c];                  // first in-kernel read -> L2 miss -> fresh LLC
        if (mc > MAXCLS) mc = MAXCLS;
        if (ht == 0) mcs[h] = mc;

        float vsum = 0.f;
        if (ht < mc) {
            int r = list[c * MAXCLS + ht];
            memH[ht] = r;
#pragma unroll
            for (int jc = 0; jc < NCHUNK; jc++) vsum += Vp[(size_t)jc * NN + r];
        }
        __syncthreads();
        if (tid == 0) {
            int s = 0;
#pragma unroll
            for (int k = 0; k < 4; k++) { cum[k] = s; s += mcs[k] * mcs[k]; }
            cum[4] = s;
        }
        __syncthreads();

        // phase 1: ALL 32 16-lane groups process the 4 classes' combined pair space
        const int g = tid >> 4;           // 0..31
        const int l = tid & 15;
        const int tot = cum[4];
        for (int pp = g; pp < tot; pp += 32) {
            int k = (pp >= cum[2]) ? ((pp >= cum[3]) ? 3 : 2) : ((pp >= cum[1]) ? 1 : 0);
            int lp = pp - cum[k];
            int mck = mcs[k];
            int i = lp / mck;
            int j = lp - i * mck;
            int* memK = (int*)(sm + k * 18432);
            int ri = memK[i], rj = memK[j];
            const float4* ar = (const float4*)(a + (size_t)ri * DD) + l * 2;
            const float4* br = (const float4*)(b + (size_t)rj * DD) + l * 2;
            float4 a0 = ar[0], a1 = ar[1];
            float4 b0 = br[0], b1 = br[1];
            float s = 0.f;
            s = fmaf(a0.x, b0.x, s); s = fmaf(a0.y, b0.y, s);
            s = fmaf(a0.z, b0.z, s); s = fmaf(a0.w, b0.w, s);
            s = fmaf(a1.x, b1.x, s); s = fmaf(a1.y, b1.y, s);
            s = fmaf(a1.z, b1.z, s); s = fmaf(a1.w, b1.w, s);
            s += __shfl_xor(s, 1);
            s += __shfl_xor(s, 2);
            s += __shfl_xor(s, 4);
            s += __shfl_xor(s, 8);
            if (l == 0) ((float*)(sm + k * 18432 + 1024))[i * MAXCLS + j] = s;
        }
        __syncthreads();

        // deterministic per-row exp-sum (ascending j == previous pp-ordered atomics)
        if (ht < mc) {
            float se = 0.f;
            for (int j = 0; j < mc; j++) se += __expf(ScH[ht * MAXCLS + j]);
            VadjH[ht] = E1 * (vsum - se);
        }
        __syncthreads();

        // phase 2: one thread per ordered pair (i != j), 128 threads per quarter
        const int tot1 = mc * mc;
        float partial = 0.f;
        int   count   = 0;
        for (int pp = ht; pp < tot1; pp += 128) {
            int i = pp / mc;
            int j = pp - i * mc;
            if (i != j) {
                float hg = fmaxf(logf(VadjH[i] + VadjH[j]) - ScH[i * MAXCLS + j], 0.f);
                partial += hg * hg;
                count++;
            }
        }
        for (int off = 32; off > 0; off >>= 1) {
            partial += __shfl_down(partial, off);
            count   += __shfl_down(count, off);
        }
        if ((ht & 63) == 0) { psH[ht >> 6] = partial; csH[ht >> 6] = count; }
        __syncthreads();
        if (ht == 0) {
            st_agent(&classLoss[c], psH[0] + psH[1]);
            st_agent(&classCnt[c],  csH[0] + csH[1]);
        }
    }

    // ========== finalize: spread arrival tree; LAST block reduces, others exit ==========
    __syncthreads();   // all waves drain vmcnt -> this block's sc1 stores are at LLC
    __shared__ int amLast;
    if (tid == 0) {
        int last = 0;
        int v = __hip_atomic_fetch_add(&subcnt[sub * 32], 1,
                                       __ATOMIC_RELAXED, __HIP_MEMORY_SCOPE_AGENT);
        if (v == (NBLK / 8) - 1) {
            __hip_atomic_store(&subcnt[sub * 32], 0, __ATOMIC_RELAXED, __HIP_MEMORY_SCOPE_AGENT);
            int r = __hip_atomic_fetch_add(root, 1, __ATOMIC_RELAXED, __HIP_MEMORY_SCOPE_AGENT);
            if (r == 7) { __hip_atomic_store(root, 0, __ATOMIC_RELAXED, __HIP_MEMORY_SCOPE_AGENT); last = 1; }
        }
        amLast = last;
    }
    __syncthreads();
    if (amLast) {
        __shared__ double dred[8];
        __shared__ long long cred[8];
        const int lane = tid & 63, wvv = tid >> 6;
        double dls = 0.0;
        long long dct = 0;
        for (int k = tid; k < 1024; k += TPB) {
            dls += (double)__hip_atomic_load(&classLoss[k], __ATOMIC_RELAXED, __HIP_MEMORY_SCOPE_AGENT);
            dct += (long long)__hip_atomic_load(&classCnt[k], __ATOMIC_RELAXED, __HIP_MEMORY_SCOPE_AGENT);
        }
        for (int off = 32; off > 0; off >>= 1) {
            dls += __shfl_down(dls, off);
            dct += __shfl_down(dct, off);
        }
        if (lane == 0) { dred[wvv] = dls; cred[wvv] = dct; }
        __syncthreads();
        if (tid == 0) {
            double ls = 0.0;
            long long np = 0;
#pragma unroll
            for (int w = 0; w < 8; w++) { ls += dred[w]; np += cred[w]; }
            out[0] = (float)(ls / (2.0 * (double)np));
        }
    }
}

// ---------------- launch ----------------
extern "C" void kernel_launch(void* const* d_in, const int* in_sizes, int n_in,
                              void* d_out, int out_size, void* d_ws, size_t ws_size,
                              hipStream_t stream)
{
    const float* a      = (const float*)d_in[0];
    const float* b      = (const float*)d_in[1];
    const int*   labels = (const int*)d_in[2];
    float* out = (float*)d_out;

    char* ws = (char*)d_ws;
    // ws layout:
    //   [0, 2MB)   a_bf16 (scaled by log2e)    [2MB, 4MB)  b_bf16
    //   base2 = 4MB (first 8KB memset to 0); every barrier word on its OWN 128B line:
    //     +0     cnt[1024]              4096 B
    //     +4096  subcnt[8]  @128B stride  1 KB
    //     +5120  root
    //     +5248  gen
    //     +5376  claim[8]   @128B stride  1 KB
    //     +6400  doneg[8]   @128B stride  1 KB
    //     +8192  classLoss[1024] f32    4096 B
    //     +12288 classCnt[1024] int     4096 B
    //     +16384 list[1024*64]          256 KB
    //     +278528 Vp[8*8192] f32        256 KB
    unsigned short* abf = (unsigned short*)ws;
    unsigned short* bbf = (unsigned short*)(ws + 2097152);
    char*     base2     = ws + 4194304;
    int*      cnt       = (int*)(base2);
    int*      subcnt    = (int*)(base2 + 4096);
    int*      root      = (int*)(base2 + 5120);
    unsigned int* gen   = (unsigned int*)(base2 + 5248);
    int*      claim     = (int*)(base2 + 5376);
    unsigned int* doneg = (unsigned int*)(base2 + 6400);
    float*    classLoss = (float*)(base2 + 8192);
    int*      classCnt  = (int*)(base2 + 12288);
    int*      list      = (int*)(base2 + 16384);
    float*    Vp        = (float*)(base2 + 278528);

    (void)hipMemsetAsync(cnt, 0, 8192, stream);   // zeros cnt + all barrier state

    ml_fused_kernel<<<NBLK, TPB, 0, stream>>>(
        a, b, labels, abf, bbf, cnt, list, Vp, classLoss, classCnt, out,
        subcnt, root, gen, claim, doneg);
}